// Round 2
// baseline (344.709 us; speedup 1.0000x reference)
//
#include <hip/hip_runtime.h>
#include <hip/hip_bf16.h>
#include <cstddef>

#define N_FEATS 64
#define N_CLASSES 8

// ---------------------------------------------------------------------------
// Kernel 1: per-edge scatter of x[src] (64 feats) into agg1[dst], + degree.
// Thread layout: 64 threads per edge (f = tid&63), edge uniform per wave.
// ---------------------------------------------------------------------------
__global__ void k_scatter64(const float* __restrict__ x,
                            const int* __restrict__ src,
                            const int* __restrict__ dst,
                            float* __restrict__ agg1,
                            float* __restrict__ deg,
                            int nEdges) {
    long long t = (long long)blockIdx.x * blockDim.x + threadIdx.x;
    int e = (int)(t >> 6);
    int f = (int)(t & 63);
    if (e >= nEdges) return;
    int s = src[e];
    int d = dst[e];
    float v = x[(size_t)s * N_FEATS + f];
    atomicAdd(&agg1[(size_t)d * N_FEATS + f], v);
    if (f == 0) atomicAdd(&deg[d], 1.0f);
}

// ---------------------------------------------------------------------------
// Kernel 2: fused dense layer.
//   h[i]  = (agg1[i]/max(deg,1)) @ W_l1 + b_l1 + x[i] @ W_r1   (in LDS only)
//   p[i]  = h[i] @ W_l2     q[i] = h[i] @ W_r2                 (stored, [N,8])
// 4 nodes per 256-thread block; weights staged in LDS.
// ---------------------------------------------------------------------------
__global__ __launch_bounds__(256) void k_dense1(
        const float* __restrict__ x,
        const float* __restrict__ agg1,
        const float* __restrict__ deg,
        const float* __restrict__ Wl1,
        const float* __restrict__ bl1,
        const float* __restrict__ Wr1,
        const float* __restrict__ Wl2,
        const float* __restrict__ Wr2,
        float* __restrict__ p,
        float* __restrict__ q,
        int nNodes) {
    __shared__ float sWl[64 * 64];
    __shared__ float sWr[64 * 64];
    __shared__ float sWl2[64 * 8];
    __shared__ float sWr2[64 * 8];
    __shared__ float sb[64];
    __shared__ float sx[4][64];    // x row per node
    __shared__ float sa[4][64];    // agg1 row (already /deg) per node
    __shared__ float sh[4][64];    // h row per node

    int tid = threadIdx.x;
    for (int i = tid; i < 64 * 64; i += 256) { sWl[i] = Wl1[i]; sWr[i] = Wr1[i]; }
    for (int i = tid; i < 64 * 8;  i += 256) { sWl2[i] = Wl2[i]; sWr2[i] = Wr2[i]; }
    if (tid < 64) sb[tid] = bl1[tid];

    int slot = tid >> 6;       // 0..3
    int f    = tid & 63;
    int node = blockIdx.x * 4 + slot;
    bool valid = (node < nNodes);

    if (valid) {
        float dg  = deg[node];
        float inv = 1.0f / fmaxf(dg, 1.0f);
        sx[slot][f] = x[(size_t)node * 64 + f];
        sa[slot][f] = agg1[(size_t)node * 64 + f] * inv;
    }
    __syncthreads();

    if (valid) {
        float acc = sb[f];
        #pragma unroll
        for (int k = 0; k < 64; ++k) {
            acc += sa[slot][k] * sWl[k * 64 + f] + sx[slot][k] * sWr[k * 64 + f];
        }
        sh[slot][f] = acc;
    }
    __syncthreads();

    if (valid && f < 16) {
        int c = f & 7;
        const float* W = (f < 8) ? sWl2 : sWr2;
        float acc = 0.0f;
        #pragma unroll
        for (int k = 0; k < 64; ++k) acc += sh[slot][k] * W[k * 8 + c];
        if (f < 8) p[(size_t)node * 8 + c] = acc;
        else       q[(size_t)node * 8 + c] = acc;
    }
}

// ---------------------------------------------------------------------------
// Kernel 3: per-edge scatter of p[src] (8 feats) into agg2[dst].
// ---------------------------------------------------------------------------
__global__ void k_scatter8(const float* __restrict__ p,
                           const int* __restrict__ src,
                           const int* __restrict__ dst,
                           float* __restrict__ agg2,
                           int nEdges) {
    long long t = (long long)blockIdx.x * blockDim.x + threadIdx.x;
    int e = (int)(t >> 3);
    int c = (int)(t & 7);
    if (e >= nEdges) return;
    int s = src[e];
    int d = dst[e];
    atomicAdd(&agg2[(size_t)d * 8 + c], p[(size_t)s * 8 + c]);
}

// ---------------------------------------------------------------------------
// Kernel 4: out = agg2/max(deg,1) + q + b_l2
// ---------------------------------------------------------------------------
__global__ void k_finalize(const float* __restrict__ agg2,
                           const float* __restrict__ q,
                           const float* __restrict__ deg,
                           const float* __restrict__ bl2,
                           float* __restrict__ out,
                           int nNodes) {
    int t = blockIdx.x * blockDim.x + threadIdx.x;
    if (t >= nNodes * 8) return;
    int node = t >> 3;
    int c = t & 7;
    float inv = 1.0f / fmaxf(deg[node], 1.0f);
    out[t] = agg2[t] * inv + q[t] + bl2[c];
}

static inline size_t align256(size_t v) { return (v + 255) & ~(size_t)255; }

extern "C" void kernel_launch(void* const* d_in, const int* in_sizes, int n_in,
                              void* d_out, int out_size, void* d_ws, size_t ws_size,
                              hipStream_t stream) {
    const float* embeds = (const float*)d_in[0];
    const int*   ei     = (const int*)d_in[1];
    const float* Wl1    = (const float*)d_in[2];
    const float* bl1    = (const float*)d_in[3];
    const float* Wr1    = (const float*)d_in[4];
    const float* Wl2    = (const float*)d_in[5];
    const float* bl2    = (const float*)d_in[6];
    const float* Wr2    = (const float*)d_in[7];

    const int N = in_sizes[0] / N_FEATS;     // 50000
    const int E = in_sizes[1] / 2;           // 800000
    const int* src = ei;
    const int* dst = ei + E;

    // workspace layout
    char* ws = (char*)d_ws;
    size_t off = 0;
    float* deg  = (float*)(ws + off); off += align256((size_t)N * sizeof(float));
    float* agg1 = (float*)(ws + off); off += align256((size_t)N * 64 * sizeof(float));
    float* p    = (float*)(ws + off); off += align256((size_t)N * 8 * sizeof(float));
    float* q    = (float*)(ws + off); off += align256((size_t)N * 8 * sizeof(float));
    float* agg2 = (float*)(ws + off); off += align256((size_t)N * 8 * sizeof(float));
    (void)ws_size;

    hipMemsetAsync(deg,  0, (size_t)N * sizeof(float), stream);
    hipMemsetAsync(agg1, 0, (size_t)N * 64 * sizeof(float), stream);
    hipMemsetAsync(agg2, 0, (size_t)N * 8 * sizeof(float), stream);

    // Layer-1 scatter: 64 threads/edge
    {
        long long threads = (long long)E * 64;
        int blocks = (int)((threads + 255) / 256);
        k_scatter64<<<blocks, 256, 0, stream>>>(embeds, src, dst, agg1, deg, E);
    }
    // Fused dense: h (LDS-only) -> p,q
    {
        int blocks = (N + 3) / 4;
        k_dense1<<<blocks, 256, 0, stream>>>(embeds, agg1, deg, Wl1, bl1, Wr1,
                                             Wl2, Wr2, p, q, N);
    }
    // Layer-2 scatter: 8 threads/edge
    {
        long long threads = (long long)E * 8;
        int blocks = (int)((threads + 255) / 256);
        k_scatter8<<<blocks, 256, 0, stream>>>(p, src, dst, agg2, E);
    }
    // Finalize
    {
        int total = N * 8;
        int blocks = (total + 255) / 256;
        k_finalize<<<blocks, 256, 0, stream>>>(agg2, q, deg, bl2, (float*)d_out, N);
    }
}

// Round 3
// 330.605 us; speedup vs baseline: 1.0427x; 1.0427x over previous
//
#include <hip/hip_runtime.h>
#include <hip/hip_bf16.h>
#include <cstddef>

#define N_FEATS 64
#define N_CLASSES 8
#define NODES_PER_BLOCK 64

// ---------------------------------------------------------------------------
// Kernel 1: histogram of dst -> counts (degree)
// ---------------------------------------------------------------------------
__global__ void k_hist(const int* __restrict__ dst, int* __restrict__ counts,
                       int nEdges) {
    int e = blockIdx.x * blockDim.x + threadIdx.x;
    if (e >= nEdges) return;
    atomicAdd(&counts[dst[e]], 1);
}

// ---------------------------------------------------------------------------
// Kernel 2: single-block exclusive scan of counts -> offsets (+cursor copy)
// 1024 threads, each owns a contiguous chunk; Hillis-Steele scan of partials.
// ---------------------------------------------------------------------------
__global__ __launch_bounds__(1024) void k_scan(const int* __restrict__ counts,
                                               int* __restrict__ offsets,
                                               int* __restrict__ cursor,
                                               int n) {
    __shared__ int partial[1024];
    int tid = threadIdx.x;
    int per = (n + 1023) / 1024;
    int start = tid * per;
    int end = start + per; if (end > n) end = n;
    int s = 0;
    for (int i = start; i < end; ++i) s += counts[i];
    partial[tid] = s;
    __syncthreads();
    for (int d = 1; d < 1024; d <<= 1) {
        int t = (tid >= d) ? partial[tid - d] : 0;
        __syncthreads();
        partial[tid] += t;
        __syncthreads();
    }
    int run = (tid == 0) ? 0 : partial[tid - 1];
    for (int i = start; i < end; ++i) {
        offsets[i] = run;
        cursor[i]  = run;
        run += counts[i];
    }
}

// ---------------------------------------------------------------------------
// Kernel 3: bucket pass -> sorted_src (CSR adjacency by dst)
// ---------------------------------------------------------------------------
__global__ void k_bucket(const int* __restrict__ src, const int* __restrict__ dst,
                         int* __restrict__ cursor, int* __restrict__ sorted_src,
                         int nEdges) {
    int e = blockIdx.x * blockDim.x + threadIdx.x;
    if (e >= nEdges) return;
    int d = dst[e];
    int pos = atomicAdd(&cursor[d], 1);
    sorted_src[pos] = src[e];
}

// ---------------------------------------------------------------------------
// Kernel 4: fused layer-1 aggregation (gather, no atomics) + dense:
//   a = mean_{j->i} x_j ; h = a@Wl1 + b + x_i@Wr1 (LDS only)
//   p = h@Wl2 ; q = h@Wr2   -> stored [N,8]
// 256 threads = 4 waves; wave handles one node (lane = feature); 64 nodes/blk.
// ---------------------------------------------------------------------------
__global__ __launch_bounds__(256) void k_fused1(
        const float* __restrict__ x,
        const int* __restrict__ counts,
        const int* __restrict__ offsets,
        const int* __restrict__ sorted_src,
        const float* __restrict__ Wl1,
        const float* __restrict__ bl1,
        const float* __restrict__ Wr1,
        const float* __restrict__ Wl2,
        const float* __restrict__ Wr2,
        float* __restrict__ p,
        float* __restrict__ q,
        int nNodes) {
    __shared__ float sWl[64 * 64];
    __shared__ float sWr[64 * 64];
    __shared__ float sWl2[64 * 8];
    __shared__ float sWr2[64 * 8];
    __shared__ float sb[64];
    __shared__ float sa[4][64];
    __shared__ float sx[4][64];
    __shared__ float sh[4][64];

    int tid = threadIdx.x;
    for (int i = tid; i < 64 * 64; i += 256) { sWl[i] = Wl1[i]; sWr[i] = Wr1[i]; }
    for (int i = tid; i < 64 * 8;  i += 256) { sWl2[i] = Wl2[i]; sWr2[i] = Wr2[i]; }
    if (tid < 64) sb[tid] = bl1[tid];
    __syncthreads();

    int slot = tid >> 6;   // wave id 0..3
    int f    = tid & 63;   // feature lane

    for (int it = 0; it < NODES_PER_BLOCK / 4; ++it) {
        int node = blockIdx.x * NODES_PER_BLOCK + it * 4 + slot;
        int cnt = 0;
        if (node < nNodes) {
            cnt = counts[node];
            int off = offsets[node];
            float acc = 0.0f;
            for (int base = 0; base < cnt; base += 64) {
                int m = cnt - base; if (m > 64) m = 64;
                int id = (base + f < cnt) ? sorted_src[off + base + f] : 0;
                int i = 0;
                for (; i + 4 <= m; i += 4) {
                    int s0 = __shfl(id, i);
                    int s1 = __shfl(id, i + 1);
                    int s2 = __shfl(id, i + 2);
                    int s3 = __shfl(id, i + 3);
                    acc += x[(size_t)s0 * 64 + f];
                    acc += x[(size_t)s1 * 64 + f];
                    acc += x[(size_t)s2 * 64 + f];
                    acc += x[(size_t)s3 * 64 + f];
                }
                for (; i < m; ++i) {
                    int s0 = __shfl(id, i);
                    acc += x[(size_t)s0 * 64 + f];
                }
            }
            float inv = 1.0f / fmaxf((float)cnt, 1.0f);
            sa[slot][f] = acc * inv;
            sx[slot][f] = x[(size_t)node * 64 + f];
        }
        __syncthreads();
        if (node < nNodes) {
            float h = sb[f];
            #pragma unroll
            for (int k = 0; k < 64; ++k) {
                h += sa[slot][k] * sWl[k * 64 + f] + sx[slot][k] * sWr[k * 64 + f];
            }
            sh[slot][f] = h;
        }
        __syncthreads();
        if (node < nNodes && f < 16) {
            int c = f & 7;
            const float* W = (f < 8) ? sWl2 : sWr2;
            float acc2 = 0.0f;
            #pragma unroll
            for (int k = 0; k < 64; ++k) acc2 += sh[slot][k] * W[k * 8 + c];
            if (f < 8) p[(size_t)node * 8 + c] = acc2;
            else       q[(size_t)node * 8 + c] = acc2;
        }
        __syncthreads();
    }
}

// ---------------------------------------------------------------------------
// Kernel 5: layer-2 aggregation (gather p, L2-resident) + epilogue:
//   out = mean_{j->i} p_j + q_i + b_l2
// ---------------------------------------------------------------------------
__global__ void k_final(const float* __restrict__ p,
                        const float* __restrict__ q,
                        const int* __restrict__ counts,
                        const int* __restrict__ offsets,
                        const int* __restrict__ sorted_src,
                        const float* __restrict__ bl2,
                        float* __restrict__ out,
                        int nNodes) {
    int t = blockIdx.x * blockDim.x + threadIdx.x;
    if (t >= nNodes * 8) return;
    int node = t >> 3;
    int c = t & 7;
    int cnt = counts[node];
    int off = offsets[node];
    float acc = 0.0f;
    int i = off, end = off + cnt;
    for (; i + 2 <= end; i += 2) {
        int s0 = sorted_src[i];
        int s1 = sorted_src[i + 1];
        acc += p[(size_t)s0 * 8 + c];
        acc += p[(size_t)s1 * 8 + c];
    }
    if (i < end) acc += p[(size_t)sorted_src[i] * 8 + c];
    float inv = 1.0f / fmaxf((float)cnt, 1.0f);
    out[t] = acc * inv + q[t] + bl2[c];
}

static inline size_t align256(size_t v) { return (v + 255) & ~(size_t)255; }

extern "C" void kernel_launch(void* const* d_in, const int* in_sizes, int n_in,
                              void* d_out, int out_size, void* d_ws, size_t ws_size,
                              hipStream_t stream) {
    const float* embeds = (const float*)d_in[0];
    const int*   ei     = (const int*)d_in[1];
    const float* Wl1    = (const float*)d_in[2];
    const float* bl1    = (const float*)d_in[3];
    const float* Wr1    = (const float*)d_in[4];
    const float* Wl2    = (const float*)d_in[5];
    const float* bl2    = (const float*)d_in[6];
    const float* Wr2    = (const float*)d_in[7];

    const int N = in_sizes[0] / N_FEATS;     // 50000
    const int E = in_sizes[1] / 2;           // 800000
    const int* src = ei;
    const int* dst = ei + E;

    // workspace layout
    char* ws = (char*)d_ws;
    size_t off = 0;
    int*   counts     = (int*)(ws + off); off += align256((size_t)N * sizeof(int));
    int*   offsets    = (int*)(ws + off); off += align256((size_t)N * sizeof(int));
    int*   cursor     = (int*)(ws + off); off += align256((size_t)N * sizeof(int));
    int*   sorted_src = (int*)(ws + off); off += align256((size_t)E * sizeof(int));
    float* p          = (float*)(ws + off); off += align256((size_t)N * 8 * sizeof(float));
    float* q          = (float*)(ws + off); off += align256((size_t)N * 8 * sizeof(float));
    (void)ws_size;

    hipMemsetAsync(counts, 0, (size_t)N * sizeof(int), stream);

    {   // degree histogram
        int blocks = (E + 255) / 256;
        k_hist<<<blocks, 256, 0, stream>>>(dst, counts, E);
    }
    {   // exclusive scan -> CSR offsets
        k_scan<<<1, 1024, 0, stream>>>(counts, offsets, cursor, N);
    }
    {   // bucket sort edges by dst
        int blocks = (E + 255) / 256;
        k_bucket<<<blocks, 256, 0, stream>>>(src, dst, cursor, sorted_src, E);
    }
    {   // fused gather-aggregate + dense layers -> p, q
        int blocks = (N + NODES_PER_BLOCK - 1) / NODES_PER_BLOCK;
        k_fused1<<<blocks, 256, 0, stream>>>(embeds, counts, offsets, sorted_src,
                                             Wl1, bl1, Wr1, Wl2, Wr2, p, q, N);
    }
    {   // layer-2 gather-aggregate + epilogue
        int total = N * 8;
        int blocks = (total + 255) / 256;
        k_final<<<blocks, 256, 0, stream>>>(p, q, counts, offsets, sorted_src,
                                            bl2, (float*)d_out, N);
    }
}

// Round 4
// 310.208 us; speedup vs baseline: 1.1112x; 1.0658x over previous
//
#include <hip/hip_runtime.h>
#include <hip/hip_bf16.h>
#include <cstddef>

#define N_FEATS 64
#define NPB 64   // nodes per block in fused kernel

// ---------------------------------------------------------------------------
// Kernel 1: histogram of dst -> counts (degree), int4-vectorized
// ---------------------------------------------------------------------------
__global__ void k_hist(const int* __restrict__ dst, int* __restrict__ counts,
                       int nE4, int nEdges) {
    int t = blockIdx.x * blockDim.x + threadIdx.x;
    if (t < nE4) {
        int4 d = ((const int4*)dst)[t];
        atomicAdd(&counts[d.x], 1);
        atomicAdd(&counts[d.y], 1);
        atomicAdd(&counts[d.z], 1);
        atomicAdd(&counts[d.w], 1);
    } else if (t == nE4) {
        for (int e = nE4 * 4; e < nEdges; ++e) atomicAdd(&counts[dst[e]], 1);
    }
}

// ---------------------------------------------------------------------------
// Kernel 2: single-block exclusive scan of counts -> offsets (+cursor copy)
// ---------------------------------------------------------------------------
__global__ __launch_bounds__(1024) void k_scan(const int* __restrict__ counts,
                                               int* __restrict__ offsets,
                                               int* __restrict__ cursor,
                                               int n) {
    __shared__ int partial[1024];
    int tid = threadIdx.x;
    int per = (n + 1023) / 1024;
    int start = tid * per;
    int end = start + per; if (end > n) end = n;
    int s = 0;
    for (int i = start; i < end; ++i) s += counts[i];
    partial[tid] = s;
    __syncthreads();
    for (int d = 1; d < 1024; d <<= 1) {
        int t = (tid >= d) ? partial[tid - d] : 0;
        __syncthreads();
        partial[tid] += t;
        __syncthreads();
    }
    int run = (tid == 0) ? 0 : partial[tid - 1];
    for (int i = start; i < end; ++i) {
        offsets[i] = run;
        cursor[i]  = run;
        run += counts[i];
    }
}

// ---------------------------------------------------------------------------
// Kernel 3: bucket pass -> sorted_src (CSR adjacency by dst), int4 loads
// ---------------------------------------------------------------------------
__global__ void k_bucket(const int* __restrict__ src, const int* __restrict__ dst,
                         int* __restrict__ cursor, int* __restrict__ sorted_src,
                         int nE4, int nEdges) {
    int t = blockIdx.x * blockDim.x + threadIdx.x;
    if (t < nE4) {
        int4 s4 = ((const int4*)src)[t];
        int4 d4 = ((const int4*)dst)[t];
        int pos;
        pos = atomicAdd(&cursor[d4.x], 1); sorted_src[pos] = s4.x;
        pos = atomicAdd(&cursor[d4.y], 1); sorted_src[pos] = s4.y;
        pos = atomicAdd(&cursor[d4.z], 1); sorted_src[pos] = s4.z;
        pos = atomicAdd(&cursor[d4.w], 1); sorted_src[pos] = s4.w;
    } else if (t == nE4) {
        for (int e = nE4 * 4; e < nEdges; ++e) {
            int pos = atomicAdd(&cursor[dst[e]], 1);
            sorted_src[pos] = src[e];
        }
    }
}

// ---------------------------------------------------------------------------
// Kernel 4: fused layer-1 aggregation + dense layers.
//   wave = 1 node; lanes split 4 edge-groups x 16 float4-slots for the gather;
//   then lane = feature for h; then all-64-lane split for p/q projection.
// ---------------------------------------------------------------------------
__global__ __launch_bounds__(256) void k_fused1(
        const float* __restrict__ x,
        const int* __restrict__ counts,
        const int* __restrict__ offsets,
        const int* __restrict__ sorted_src,
        const float* __restrict__ Wl1,
        const float* __restrict__ bl1,
        const float* __restrict__ Wr1,
        const float* __restrict__ Wl2,
        const float* __restrict__ Wr2,
        float* __restrict__ p,
        float* __restrict__ q,
        int nNodes) {
    __shared__ float sWl[64 * 64];
    __shared__ float sWr[64 * 64];
    __shared__ float sWl2[64 * 9];   // padded stride 9 (bank-spread)
    __shared__ float sWr2[64 * 9];
    __shared__ __align__(16) float sa[4][64];
    __shared__ __align__(16) float sx[4][64];
    __shared__ float sh[4][64];

    int tid = threadIdx.x;
    for (int i = tid; i < 64 * 64; i += 256) { sWl[i] = Wl1[i]; sWr[i] = Wr1[i]; }
    for (int i = tid; i < 64 * 8;  i += 256) {
        int k = i >> 3, c = i & 7;
        sWl2[k * 9 + c] = Wl2[i];
        sWr2[k * 9 + c] = Wr2[i];
    }
    int slot = tid >> 6;   // wave id 0..3
    int f    = tid & 63;
    float bias = bl1[f];
    __syncthreads();

    int g  = f >> 4;       // edge group 0..3
    int t4 = f & 15;       // float4 slot within a 64-float row
    const float4* xv4 = (const float4*)x;

    for (int it = 0; it < NPB / 4; ++it) {
        int node = blockIdx.x * NPB + it * 4 + slot;
        int cnt = 0, off = 0;
        if (node < nNodes) { cnt = counts[node]; off = offsets[node]; }

        // ---- gather: 4 edges in parallel, float4 per 16 lanes ----
        float ax = 0.f, ay = 0.f, az = 0.f, aw = 0.f;
        int id = (g < cnt) ? sorted_src[off + g] : -1;
        for (int base = 0; base < cnt; base += 4) {
            int en  = base + 4 + g;
            int idn = (en < cnt) ? sorted_src[off + en] : -1;
            if (id >= 0) {
                float4 r = xv4[(size_t)id * 16 + t4];
                ax += r.x; ay += r.y; az += r.z; aw += r.w;
            }
            id = idn;
        }
        ax += __shfl_xor(ax, 16); ay += __shfl_xor(ay, 16);
        az += __shfl_xor(az, 16); aw += __shfl_xor(aw, 16);
        ax += __shfl_xor(ax, 32); ay += __shfl_xor(ay, 32);
        az += __shfl_xor(az, 32); aw += __shfl_xor(aw, 32);

        if (node < nNodes) {
            float inv = 1.0f / fmaxf((float)cnt, 1.0f);
            if (g == 0) {
                float4 o; o.x = ax * inv; o.y = ay * inv; o.z = az * inv; o.w = aw * inv;
                ((float4*)sa[slot])[t4] = o;
            } else if (g == 1) {
                float4 xr = xv4[(size_t)node * 16 + t4];
                ((float4*)sx[slot])[t4] = xr;
            }
        }
        __syncthreads();   // B1

        // ---- dense: h = a@Wl1 + b + x@Wr1 (lane = out feature) ----
        if (node < nNodes) {
            float h = bias;
            #pragma unroll
            for (int k0 = 0; k0 < 64; k0 += 4) {
                float4 av = *(const float4*)&sa[slot][k0];
                float4 xr = *(const float4*)&sx[slot][k0];
                h += av.x * sWl[(k0 + 0) * 64 + f] + xr.x * sWr[(k0 + 0) * 64 + f];
                h += av.y * sWl[(k0 + 1) * 64 + f] + xr.y * sWr[(k0 + 1) * 64 + f];
                h += av.z * sWl[(k0 + 2) * 64 + f] + xr.z * sWr[(k0 + 2) * 64 + f];
                h += av.w * sWl[(k0 + 3) * 64 + f] + xr.w * sWr[(k0 + 3) * 64 + f];
            }
            sh[slot][f] = h;
        }
        __syncthreads();   // B2

        // ---- p/q projection: all 64 lanes: pq=f>>5, c=(f>>2)&7, kp=f&3 ----
        if (node < nNodes) {
            int pq = f >> 5, c = (f >> 2) & 7, kp = f & 3;
            const float* W = pq ? sWr2 : sWl2;
            float a2 = 0.f;
            #pragma unroll
            for (int kk = 0; kk < 16; ++kk) {
                int k = kp * 16 + kk;
                a2 += sh[slot][k] * W[k * 9 + c];
            }
            a2 += __shfl_xor(a2, 1);
            a2 += __shfl_xor(a2, 2);
            if (kp == 0) {
                if (pq == 0) p[(size_t)node * 8 + c] = a2;
                else         q[(size_t)node * 8 + c] = a2;
            }
        }
        // no barrier needed: next pass only writes sa/sx (read before B2 by
        // this same wave; all LDS dataflow here is intra-wave per slot)
    }
}

// ---------------------------------------------------------------------------
// Kernel 5: layer-2 gather-mean of p + epilogue. 2 nodes per wave:
//   half = lane>>5, 4 edge-groups x 8 channels per node.
// ---------------------------------------------------------------------------
__global__ __launch_bounds__(256) void k_final(
        const float* __restrict__ pv,
        const float* __restrict__ qv,
        const int* __restrict__ counts,
        const int* __restrict__ offsets,
        const int* __restrict__ sorted_src,
        const float* __restrict__ bl2,
        float* __restrict__ out,
        int nNodes) {
    int tid  = threadIdx.x;
    int wave = tid >> 6, lane = tid & 63;
    int half = lane >> 5;          // which of the 2 nodes
    int eg   = (lane >> 3) & 3;    // edge group 0..3
    int c    = lane & 7;           // channel
    int node = blockIdx.x * 8 + wave * 2 + half;
    if (node >= nNodes) return;
    int cnt = counts[node], off = offsets[node];
    float acc = 0.f;
    for (int base = 0; base < cnt; base += 4) {
        int e = base + eg;
        if (e < cnt) {
            int s = sorted_src[off + e];
            acc += pv[(size_t)s * 8 + c];
        }
    }
    acc += __shfl_xor(acc, 8);
    acc += __shfl_xor(acc, 16);
    if (eg == 0) {
        float inv = 1.0f / fmaxf((float)cnt, 1.0f);
        out[(size_t)node * 8 + c] = acc * inv + qv[(size_t)node * 8 + c] + bl2[c];
    }
}

static inline size_t align256(size_t v) { return (v + 255) & ~(size_t)255; }

extern "C" void kernel_launch(void* const* d_in, const int* in_sizes, int n_in,
                              void* d_out, int out_size, void* d_ws, size_t ws_size,
                              hipStream_t stream) {
    const float* embeds = (const float*)d_in[0];
    const int*   ei     = (const int*)d_in[1];
    const float* Wl1    = (const float*)d_in[2];
    const float* bl1    = (const float*)d_in[3];
    const float* Wr1    = (const float*)d_in[4];
    const float* Wl2    = (const float*)d_in[5];
    const float* bl2    = (const float*)d_in[6];
    const float* Wr2    = (const float*)d_in[7];

    const int N = in_sizes[0] / N_FEATS;     // 50000
    const int E = in_sizes[1] / 2;           // 800000
    const int* src = ei;
    const int* dst = ei + E;
    const int E4 = E / 4;

    // workspace layout
    char* ws = (char*)d_ws;
    size_t off = 0;
    int*   counts     = (int*)(ws + off); off += align256((size_t)N * sizeof(int));
    int*   offsets    = (int*)(ws + off); off += align256((size_t)N * sizeof(int));
    int*   cursor     = (int*)(ws + off); off += align256((size_t)N * sizeof(int));
    int*   sorted_src = (int*)(ws + off); off += align256((size_t)E * sizeof(int));
    float* p          = (float*)(ws + off); off += align256((size_t)N * 8 * sizeof(float));
    float* q          = (float*)(ws + off); off += align256((size_t)N * 8 * sizeof(float));
    (void)ws_size;

    hipMemsetAsync(counts, 0, (size_t)N * sizeof(int), stream);

    {   // degree histogram (int4)
        int threads = E4 + 1;
        int blocks = (threads + 255) / 256;
        k_hist<<<blocks, 256, 0, stream>>>(dst, counts, E4, E);
    }
    {   // exclusive scan -> CSR offsets
        k_scan<<<1, 1024, 0, stream>>>(counts, offsets, cursor, N);
    }
    {   // bucket sort edges by dst (int4)
        int threads = E4 + 1;
        int blocks = (threads + 255) / 256;
        k_bucket<<<blocks, 256, 0, stream>>>(src, dst, cursor, sorted_src, E4, E);
    }
    {   // fused gather-aggregate + dense layers -> p, q
        int blocks = (N + NPB - 1) / NPB;
        k_fused1<<<blocks, 256, 0, stream>>>(embeds, counts, offsets, sorted_src,
                                             Wl1, bl1, Wr1, Wl2, Wr2, p, q, N);
    }
    {   // layer-2 gather-aggregate + epilogue (8 nodes/block)
        int blocks = (N + 7) / 8;
        k_final<<<blocks, 256, 0, stream>>>(p, q, counts, offsets, sorted_src,
                                            bl2, (float*)d_out, N);
    }
}

// Round 5
// 211.382 us; speedup vs baseline: 1.6307x; 1.4675x over previous
//
#include <hip/hip_runtime.h>
#include <hip/hip_bf16.h>
#include <cstddef>

#define N_FEATS 64
#define NPB 64   // nodes per block in fused kernel

// ---------------------------------------------------------------------------
// Kernel 1: histogram of dst -> counts (degree), int4-vectorized
// ---------------------------------------------------------------------------
__global__ void k_hist(const int* __restrict__ dst, int* __restrict__ counts,
                       int nE4, int nEdges) {
    int t = blockIdx.x * blockDim.x + threadIdx.x;
    if (t < nE4) {
        int4 d = ((const int4*)dst)[t];
        atomicAdd(&counts[d.x], 1);
        atomicAdd(&counts[d.y], 1);
        atomicAdd(&counts[d.z], 1);
        atomicAdd(&counts[d.w], 1);
    } else if (t == nE4) {
        for (int e = nE4 * 4; e < nEdges; ++e) atomicAdd(&counts[dst[e]], 1);
    }
}

// ---------------------------------------------------------------------------
// Two-level scan: (a) per-block reduce, (b) root scan of partials,
// (c) per-block exclusive scan + base -> offsets & cursor.
// ---------------------------------------------------------------------------
__global__ __launch_bounds__(256) void k_partial(const int* __restrict__ counts,
                                                 int* __restrict__ partials, int n) {
    __shared__ int sdata[256];
    int tid = threadIdx.x;
    int i = blockIdx.x * 256 + tid;
    sdata[tid] = (i < n) ? counts[i] : 0;
    __syncthreads();
    for (int s = 128; s > 0; s >>= 1) {
        if (tid < s) sdata[tid] += sdata[tid + s];
        __syncthreads();
    }
    if (tid == 0) partials[blockIdx.x] = sdata[0];
}

__global__ __launch_bounds__(256) void k_root(int* __restrict__ partials, int nb) {
    __shared__ int sdata[256];
    int tid = threadIdx.x;
    sdata[tid] = (tid < nb) ? partials[tid] : 0;
    __syncthreads();
    for (int d = 1; d < 256; d <<= 1) {
        int t = (tid >= d) ? sdata[tid - d] : 0;
        __syncthreads();
        sdata[tid] += t;
        __syncthreads();
    }
    if (tid < nb) partials[tid] = (tid == 0) ? 0 : sdata[tid - 1];
}

__global__ __launch_bounds__(256) void k_offsets(const int* __restrict__ counts,
                                                 const int* __restrict__ partials,
                                                 int* __restrict__ offsets,
                                                 int* __restrict__ cursor, int n) {
    __shared__ int sdata[256];
    int tid = threadIdx.x;
    int i = blockIdx.x * 256 + tid;
    int v = (i < n) ? counts[i] : 0;
    sdata[tid] = v;
    __syncthreads();
    for (int d = 1; d < 256; d <<= 1) {
        int t = (tid >= d) ? sdata[tid - d] : 0;
        __syncthreads();
        sdata[tid] += t;
        __syncthreads();
    }
    int excl = sdata[tid] - v + partials[blockIdx.x];
    if (i < n) { offsets[i] = excl; cursor[i] = excl; }
}

// ---------------------------------------------------------------------------
// Kernel 3: bucket pass -> sorted_src (CSR adjacency by dst), int4 loads
// ---------------------------------------------------------------------------
__global__ void k_bucket(const int* __restrict__ src, const int* __restrict__ dst,
                         int* __restrict__ cursor, int* __restrict__ sorted_src,
                         int nE4, int nEdges) {
    int t = blockIdx.x * blockDim.x + threadIdx.x;
    if (t < nE4) {
        int4 s4 = ((const int4*)src)[t];
        int4 d4 = ((const int4*)dst)[t];
        int pos;
        pos = atomicAdd(&cursor[d4.x], 1); sorted_src[pos] = s4.x;
        pos = atomicAdd(&cursor[d4.y], 1); sorted_src[pos] = s4.y;
        pos = atomicAdd(&cursor[d4.z], 1); sorted_src[pos] = s4.z;
        pos = atomicAdd(&cursor[d4.w], 1); sorted_src[pos] = s4.w;
    } else if (t == nE4) {
        for (int e = nE4 * 4; e < nEdges; ++e) {
            int pos = atomicAdd(&cursor[dst[e]], 1);
            sorted_src[pos] = src[e];
        }
    }
}

// ---------------------------------------------------------------------------
// Kernel 4: fused layer-1 aggregation + dense layers.
//   wave = 1 node; lanes split 4 edge-groups x 16 float4-slots for the gather;
//   then lane = feature for h; then all-64-lane split for p/q projection.
// ---------------------------------------------------------------------------
__global__ __launch_bounds__(256) void k_fused1(
        const float* __restrict__ x,
        const int* __restrict__ counts,
        const int* __restrict__ offsets,
        const int* __restrict__ sorted_src,
        const float* __restrict__ Wl1,
        const float* __restrict__ bl1,
        const float* __restrict__ Wr1,
        const float* __restrict__ Wl2,
        const float* __restrict__ Wr2,
        float* __restrict__ p,
        float* __restrict__ q,
        int nNodes) {
    __shared__ float sWl[64 * 64];
    __shared__ float sWr[64 * 64];
    __shared__ float sWl2[64 * 9];   // padded stride 9 (bank-spread)
    __shared__ float sWr2[64 * 9];
    __shared__ __align__(16) float sa[4][64];
    __shared__ __align__(16) float sx[4][64];
    __shared__ float sh[4][64];

    int tid = threadIdx.x;
    for (int i = tid; i < 64 * 64; i += 256) { sWl[i] = Wl1[i]; sWr[i] = Wr1[i]; }
    for (int i = tid; i < 64 * 8;  i += 256) {
        int k = i >> 3, c = i & 7;
        sWl2[k * 9 + c] = Wl2[i];
        sWr2[k * 9 + c] = Wr2[i];
    }
    int slot = tid >> 6;   // wave id 0..3
    int f    = tid & 63;
    float bias = bl1[f];
    __syncthreads();

    int g  = f >> 4;       // edge group 0..3
    int t4 = f & 15;       // float4 slot within a 64-float row
    const float4* xv4 = (const float4*)x;

    for (int it = 0; it < NPB / 4; ++it) {
        int node = blockIdx.x * NPB + it * 4 + slot;
        int cnt = 0, off = 0;
        if (node < nNodes) { cnt = counts[node]; off = offsets[node]; }

        // ---- gather: 4 edges in parallel, float4 per 16 lanes ----
        float ax = 0.f, ay = 0.f, az = 0.f, aw = 0.f;
        int id = (g < cnt) ? sorted_src[off + g] : -1;
        for (int base = 0; base < cnt; base += 4) {
            int en  = base + 4 + g;
            int idn = (en < cnt) ? sorted_src[off + en] : -1;
            if (id >= 0) {
                float4 r = xv4[(size_t)id * 16 + t4];
                ax += r.x; ay += r.y; az += r.z; aw += r.w;
            }
            id = idn;
        }
        ax += __shfl_xor(ax, 16); ay += __shfl_xor(ay, 16);
        az += __shfl_xor(az, 16); aw += __shfl_xor(aw, 16);
        ax += __shfl_xor(ax, 32); ay += __shfl_xor(ay, 32);
        az += __shfl_xor(az, 32); aw += __shfl_xor(aw, 32);

        if (node < nNodes) {
            float inv = 1.0f / fmaxf((float)cnt, 1.0f);
            if (g == 0) {
                float4 o; o.x = ax * inv; o.y = ay * inv; o.z = az * inv; o.w = aw * inv;
                ((float4*)sa[slot])[t4] = o;
            } else if (g == 1) {
                float4 xr = xv4[(size_t)node * 16 + t4];
                ((float4*)sx[slot])[t4] = xr;
            }
        }
        __syncthreads();   // B1

        // ---- dense: h = a@Wl1 + b + x@Wr1 (lane = out feature) ----
        if (node < nNodes) {
            float h = bias;
            #pragma unroll
            for (int k0 = 0; k0 < 64; k0 += 4) {
                float4 av = *(const float4*)&sa[slot][k0];
                float4 xr = *(const float4*)&sx[slot][k0];
                h += av.x * sWl[(k0 + 0) * 64 + f] + xr.x * sWr[(k0 + 0) * 64 + f];
                h += av.y * sWl[(k0 + 1) * 64 + f] + xr.y * sWr[(k0 + 1) * 64 + f];
                h += av.z * sWl[(k0 + 2) * 64 + f] + xr.z * sWr[(k0 + 2) * 64 + f];
                h += av.w * sWl[(k0 + 3) * 64 + f] + xr.w * sWr[(k0 + 3) * 64 + f];
            }
            sh[slot][f] = h;
        }
        __syncthreads();   // B2

        // ---- p/q projection: all 64 lanes: pq=f>>5, c=(f>>2)&7, kp=f&3 ----
        if (node < nNodes) {
            int pq = f >> 5, c = (f >> 2) & 7, kp = f & 3;
            const float* W = pq ? sWr2 : sWl2;
            float a2 = 0.f;
            #pragma unroll
            for (int kk = 0; kk < 16; ++kk) {
                int k = kp * 16 + kk;
                a2 += sh[slot][k] * W[k * 9 + c];
            }
            a2 += __shfl_xor(a2, 1);
            a2 += __shfl_xor(a2, 2);
            if (kp == 0) {
                if (pq == 0) p[(size_t)node * 8 + c] = a2;
                else         q[(size_t)node * 8 + c] = a2;
            }
        }
        // no barrier needed: next pass only writes sa/sx (read before B2 by
        // this same wave; all LDS dataflow here is intra-wave per slot)
    }
}

// ---------------------------------------------------------------------------
// Kernel 5: layer-2 gather-mean of p + epilogue. 2 nodes per wave:
//   half = lane>>5, 4 edge-groups x 8 channels per node.
// ---------------------------------------------------------------------------
__global__ __launch_bounds__(256) void k_final(
        const float* __restrict__ pv,
        const float* __restrict__ qv,
        const int* __restrict__ counts,
        const int* __restrict__ offsets,
        const int* __restrict__ sorted_src,
        const float* __restrict__ bl2,
        float* __restrict__ out,
        int nNodes) {
    int tid  = threadIdx.x;
    int wave = tid >> 6, lane = tid & 63;
    int half = lane >> 5;          // which of the 2 nodes
    int eg   = (lane >> 3) & 3;    // edge group 0..3
    int c    = lane & 7;           // channel
    int node = blockIdx.x * 8 + wave * 2 + half;
    if (node >= nNodes) return;
    int cnt = counts[node], off = offsets[node];
    float acc = 0.f;
    for (int base = 0; base < cnt; base += 4) {
        int e = base + eg;
        if (e < cnt) {
            int s = sorted_src[off + e];
            acc += pv[(size_t)s * 8 + c];
        }
    }
    acc += __shfl_xor(acc, 8);
    acc += __shfl_xor(acc, 16);
    if (eg == 0) {
        float inv = 1.0f / fmaxf((float)cnt, 1.0f);
        out[(size_t)node * 8 + c] = acc * inv + qv[(size_t)node * 8 + c] + bl2[c];
    }
}

static inline size_t align256(size_t v) { return (v + 255) & ~(size_t)255; }

extern "C" void kernel_launch(void* const* d_in, const int* in_sizes, int n_in,
                              void* d_out, int out_size, void* d_ws, size_t ws_size,
                              hipStream_t stream) {
    const float* embeds = (const float*)d_in[0];
    const int*   ei     = (const int*)d_in[1];
    const float* Wl1    = (const float*)d_in[2];
    const float* bl1    = (const float*)d_in[3];
    const float* Wr1    = (const float*)d_in[4];
    const float* Wl2    = (const float*)d_in[5];
    const float* bl2    = (const float*)d_in[6];
    const float* Wr2    = (const float*)d_in[7];

    const int N = in_sizes[0] / N_FEATS;     // 50000
    const int E = in_sizes[1] / 2;           // 800000
    const int* src = ei;
    const int* dst = ei + E;
    const int E4 = E / 4;
    const int NB = (N + 255) / 256;          // scan blocks (196 for 50k)

    // workspace layout
    char* ws = (char*)d_ws;
    size_t off = 0;
    int*   counts     = (int*)(ws + off); off += align256((size_t)N * sizeof(int));
    int*   offsets    = (int*)(ws + off); off += align256((size_t)N * sizeof(int));
    int*   cursor     = (int*)(ws + off); off += align256((size_t)N * sizeof(int));
    int*   partials   = (int*)(ws + off); off += align256((size_t)256 * sizeof(int));
    int*   sorted_src = (int*)(ws + off); off += align256((size_t)E * sizeof(int));
    float* p          = (float*)(ws + off); off += align256((size_t)N * 8 * sizeof(float));
    float* q          = (float*)(ws + off); off += align256((size_t)N * 8 * sizeof(float));
    (void)ws_size;

    hipMemsetAsync(counts, 0, (size_t)N * sizeof(int), stream);

    {   // degree histogram (int4)
        int threads = E4 + 1;
        int blocks = (threads + 255) / 256;
        k_hist<<<blocks, 256, 0, stream>>>(dst, counts, E4, E);
    }
    // two-level exclusive scan -> offsets, cursor
    k_partial<<<NB, 256, 0, stream>>>(counts, partials, N);
    k_root<<<1, 256, 0, stream>>>(partials, NB);
    k_offsets<<<NB, 256, 0, stream>>>(counts, partials, offsets, cursor, N);
    {   // bucket sort edges by dst (int4)
        int threads = E4 + 1;
        int blocks = (threads + 255) / 256;
        k_bucket<<<blocks, 256, 0, stream>>>(src, dst, cursor, sorted_src, E4, E);
    }
    {   // fused gather-aggregate + dense layers -> p, q
        int blocks = (N + NPB - 1) / NPB;
        k_fused1<<<blocks, 256, 0, stream>>>(embeds, counts, offsets, sorted_src,
                                             Wl1, bl1, Wr1, Wl2, Wr2, p, q, N);
    }
    {   // layer-2 gather-aggregate + epilogue (8 nodes/block)
        int blocks = (N + 7) / 8;
        k_final<<<blocks, 256, 0, stream>>>(p, q, counts, offsets, sorted_src,
                                            bl2, (float*)d_out, N);
    }
}

// Round 6
// 184.011 us; speedup vs baseline: 1.8733x; 1.1487x over previous
//
#include <hip/hip_runtime.h>
#include <hip/hip_bf16.h>
#include <cstddef>

#define N_FEATS 64

// ---------------------------------------------------------------------------
// Kernel 1: histogram of dst -> counts (degree), int4-vectorized
// ---------------------------------------------------------------------------
__global__ void k_hist(const int* __restrict__ dst, int* __restrict__ counts,
                       int nE4, int nEdges) {
    int t = blockIdx.x * blockDim.x + threadIdx.x;
    if (t < nE4) {
        int4 d = ((const int4*)dst)[t];
        atomicAdd(&counts[d.x], 1);
        atomicAdd(&counts[d.y], 1);
        atomicAdd(&counts[d.z], 1);
        atomicAdd(&counts[d.w], 1);
    } else if (t == nE4) {
        for (int e = nE4 * 4; e < nEdges; ++e) atomicAdd(&counts[dst[e]], 1);
    }
}

// ---------------------------------------------------------------------------
// Two-level scan: (a) per-block reduce, (b) root scan of partials,
// (c) per-block exclusive scan + base -> offsets & cursor.
// ---------------------------------------------------------------------------
__global__ __launch_bounds__(256) void k_partial(const int* __restrict__ counts,
                                                 int* __restrict__ partials, int n) {
    __shared__ int sdata[256];
    int tid = threadIdx.x;
    int i = blockIdx.x * 256 + tid;
    sdata[tid] = (i < n) ? counts[i] : 0;
    __syncthreads();
    for (int s = 128; s > 0; s >>= 1) {
        if (tid < s) sdata[tid] += sdata[tid + s];
        __syncthreads();
    }
    if (tid == 0) partials[blockIdx.x] = sdata[0];
}

__global__ __launch_bounds__(256) void k_root(int* __restrict__ partials, int nb) {
    __shared__ int sdata[256];
    int tid = threadIdx.x;
    sdata[tid] = (tid < nb) ? partials[tid] : 0;
    __syncthreads();
    for (int d = 1; d < 256; d <<= 1) {
        int t = (tid >= d) ? sdata[tid - d] : 0;
        __syncthreads();
        sdata[tid] += t;
        __syncthreads();
    }
    if (tid < nb) partials[tid] = (tid == 0) ? 0 : sdata[tid - 1];
}

__global__ __launch_bounds__(256) void k_offsets(const int* __restrict__ counts,
                                                 const int* __restrict__ partials,
                                                 int* __restrict__ offsets,
                                                 int* __restrict__ cursor, int n) {
    __shared__ int sdata[256];
    int tid = threadIdx.x;
    int i = blockIdx.x * 256 + tid;
    int v = (i < n) ? counts[i] : 0;
    sdata[tid] = v;
    __syncthreads();
    for (int d = 1; d < 256; d <<= 1) {
        int t = (tid >= d) ? sdata[tid - d] : 0;
        __syncthreads();
        sdata[tid] += t;
        __syncthreads();
    }
    int excl = sdata[tid] - v + partials[blockIdx.x];
    if (i < n) { offsets[i] = excl; cursor[i] = excl; }
}

// ---------------------------------------------------------------------------
// Kernel 3: bucket pass -> sorted_src (CSR adjacency by dst), int4 loads
// ---------------------------------------------------------------------------
__global__ void k_bucket(const int* __restrict__ src, const int* __restrict__ dst,
                         int* __restrict__ cursor, int* __restrict__ sorted_src,
                         int nE4, int nEdges) {
    int t = blockIdx.x * blockDim.x + threadIdx.x;
    if (t < nE4) {
        int4 s4 = ((const int4*)src)[t];
        int4 d4 = ((const int4*)dst)[t];
        int pos;
        pos = atomicAdd(&cursor[d4.x], 1); sorted_src[pos] = s4.x;
        pos = atomicAdd(&cursor[d4.y], 1); sorted_src[pos] = s4.y;
        pos = atomicAdd(&cursor[d4.z], 1); sorted_src[pos] = s4.z;
        pos = atomicAdd(&cursor[d4.w], 1); sorted_src[pos] = s4.w;
    } else if (t == nE4) {
        for (int e = nE4 * 4; e < nEdges; ++e) {
            int pos = atomicAdd(&cursor[dst[e]], 1);
            sorted_src[pos] = src[e];
        }
    }
}

// ---------------------------------------------------------------------------
// Kernel 4 (new): dense projections  u = X@Wl1,  v = X@Wr1 + b.
// lane = node; x row held in 64 VGPRs; weights read as uniform-address LDS
// broadcasts (conflict-free); out-features in chunks of 8 (16 indep accs).
// ---------------------------------------------------------------------------
__global__ __launch_bounds__(128) void k_gemm(
        const float* __restrict__ x,
        const float* __restrict__ Wl1,
        const float* __restrict__ bl1,
        const float* __restrict__ Wr1,
        float* __restrict__ u,
        float* __restrict__ v,
        int nNodes) {
    __shared__ float sWl[64 * 64];
    __shared__ float sWr[64 * 64];
    __shared__ float sb[64];

    int tid = threadIdx.x;
    for (int i = tid; i < 1024; i += 128) {
        ((float4*)sWl)[i] = ((const float4*)Wl1)[i];
        ((float4*)sWr)[i] = ((const float4*)Wr1)[i];
    }
    if (tid < 64) sb[tid] = bl1[tid];
    __syncthreads();

    int wave = tid >> 6, lane = tid & 63;
    int node = blockIdx.x * 128 + wave * 64 + lane;
    bool valid = (node < nNodes);

    float4 vx[16];
    const float4* xv4 = (const float4*)x;
    if (valid) {
        #pragma unroll
        for (int j = 0; j < 16; ++j) vx[j] = xv4[(size_t)node * 16 + j];
    } else {
        #pragma unroll
        for (int j = 0; j < 16; ++j) vx[j] = make_float4(0.f, 0.f, 0.f, 0.f);
    }

    #pragma unroll 1
    for (int fc = 0; fc < 8; ++fc) {
        int f0 = fc * 8;
        float au0=0.f,au1=0.f,au2=0.f,au3=0.f,au4=0.f,au5=0.f,au6=0.f,au7=0.f;
        float av0,av1,av2,av3,av4,av5,av6,av7;
        {
            float4 b0 = *(const float4*)&sb[f0];
            float4 b1 = *(const float4*)&sb[f0 + 4];
            av0=b0.x; av1=b0.y; av2=b0.z; av3=b0.w;
            av4=b1.x; av5=b1.y; av6=b1.z; av7=b1.w;
        }
        #pragma unroll
        for (int k4 = 0; k4 < 16; ++k4) {
            float4 xq = vx[k4];
            #pragma unroll
            for (int kk = 0; kk < 4; ++kk) {
                int k = k4 * 4 + kk;
                float xk = (kk == 0) ? xq.x : (kk == 1) ? xq.y : (kk == 2) ? xq.z : xq.w;
                float4 wl0 = *(const float4*)&sWl[k * 64 + f0];
                float4 wl1v = *(const float4*)&sWl[k * 64 + f0 + 4];
                float4 wr0 = *(const float4*)&sWr[k * 64 + f0];
                float4 wr1v = *(const float4*)&sWr[k * 64 + f0 + 4];
                au0 += xk * wl0.x;  au1 += xk * wl0.y;
                au2 += xk * wl0.z;  au3 += xk * wl0.w;
                au4 += xk * wl1v.x; au5 += xk * wl1v.y;
                au6 += xk * wl1v.z; au7 += xk * wl1v.w;
                av0 += xk * wr0.x;  av1 += xk * wr0.y;
                av2 += xk * wr0.z;  av3 += xk * wr0.w;
                av4 += xk * wr1v.x; av5 += xk * wr1v.y;
                av6 += xk * wr1v.z; av7 += xk * wr1v.w;
            }
        }
        if (valid) {
            float4 s;
            s.x=au0; s.y=au1; s.z=au2; s.w=au3;
            ((float4*)u)[(size_t)node * 16 + fc * 2]     = s;
            s.x=au4; s.y=au5; s.z=au6; s.w=au7;
            ((float4*)u)[(size_t)node * 16 + fc * 2 + 1] = s;
            s.x=av0; s.y=av1; s.z=av2; s.w=av3;
            ((float4*)v)[(size_t)node * 16 + fc * 2]     = s;
            s.x=av4; s.y=av5; s.z=av6; s.w=av7;
            ((float4*)v)[(size_t)node * 16 + fc * 2 + 1] = s;
        }
    }
}

// ---------------------------------------------------------------------------
// Kernel 5 (new): h = mean-gather(u) + v;  p = h@Wl2; q = h@Wr2.
// 1 node per wave, 4 waves/block, no __syncthreads in hot path (all LDS
// dataflow intra-wave). Tiny LDS -> full occupancy hides gather latency.
// ---------------------------------------------------------------------------
__global__ __launch_bounds__(256) void k_gather1(
        const float* __restrict__ u,
        const float* __restrict__ v,
        const int* __restrict__ counts,
        const int* __restrict__ offsets,
        const int* __restrict__ sorted_src,
        const float* __restrict__ Wl2,
        const float* __restrict__ Wr2,
        float* __restrict__ p,
        float* __restrict__ q,
        int nNodes) {
    __shared__ float sWl2[64 * 9];   // padded stride 9
    __shared__ float sWr2[64 * 9];
    __shared__ float sh[4][64];

    int tid = threadIdx.x;
    for (int i = tid; i < 64 * 8; i += 256) {
        int k = i >> 3, c = i & 7;
        sWl2[k * 9 + c] = Wl2[i];
        sWr2[k * 9 + c] = Wr2[i];
    }
    __syncthreads();   // weights ready (only cross-wave dependency)

    int slot = tid >> 6;   // wave 0..3
    int f    = tid & 63;
    int g    = f >> 4;     // edge group
    int t4   = f & 15;     // float4 slot
    const float4* uv4 = (const float4*)u;

    int node = blockIdx.x * 4 + slot;
    if (node >= nNodes) return;
    int cnt = counts[node];
    int off = offsets[node];

    // gather-mean of u: 4 edges in parallel, float4 per 16 lanes
    float ax = 0.f, ay = 0.f, az = 0.f, aw = 0.f;
    int id = (g < cnt) ? sorted_src[off + g] : -1;
    for (int base = 0; base < cnt; base += 4) {
        int en  = base + 4 + g;
        int idn = (en < cnt) ? sorted_src[off + en] : -1;
        if (id >= 0) {
            float4 r = uv4[(size_t)id * 16 + t4];
            ax += r.x; ay += r.y; az += r.z; aw += r.w;
        }
        id = idn;
    }
    ax += __shfl_xor(ax, 16); ay += __shfl_xor(ay, 16);
    az += __shfl_xor(az, 16); aw += __shfl_xor(aw, 16);
    ax += __shfl_xor(ax, 32); ay += __shfl_xor(ay, 32);
    az += __shfl_xor(az, 32); aw += __shfl_xor(aw, 32);

    if (g == 0) {
        float inv = 1.0f / fmaxf((float)cnt, 1.0f);
        float4 vr = ((const float4*)v)[(size_t)node * 16 + t4];
        float4 o;
        o.x = ax * inv + vr.x; o.y = ay * inv + vr.y;
        o.z = az * inv + vr.z; o.w = aw * inv + vr.w;
        ((float4*)sh[slot])[t4] = o;
    }
    // intra-wave LDS dependency: compiler orders via lgkmcnt; no barrier.

    int pq = f >> 5, c = (f >> 2) & 7, kp = f & 3;
    const float* W = pq ? sWr2 : sWl2;
    float a2 = 0.f;
    #pragma unroll
    for (int kk = 0; kk < 16; ++kk) {
        int k = kp * 16 + kk;
        a2 += sh[slot][k] * W[k * 9 + c];
    }
    a2 += __shfl_xor(a2, 1);
    a2 += __shfl_xor(a2, 2);
    if (kp == 0) {
        if (pq == 0) p[(size_t)node * 8 + c] = a2;
        else         q[(size_t)node * 8 + c] = a2;
    }
}

// ---------------------------------------------------------------------------
// Kernel 6: layer-2 gather-mean of p + epilogue. 2 nodes per wave.
// ---------------------------------------------------------------------------
__global__ __launch_bounds__(256) void k_final(
        const float* __restrict__ pv,
        const float* __restrict__ qv,
        const int* __restrict__ counts,
        const int* __restrict__ offsets,
        const int* __restrict__ sorted_src,
        const float* __restrict__ bl2,
        float* __restrict__ out,
        int nNodes) {
    int tid  = threadIdx.x;
    int wave = tid >> 6, lane = tid & 63;
    int half = lane >> 5;
    int eg   = (lane >> 3) & 3;
    int c    = lane & 7;
    int node = blockIdx.x * 8 + wave * 2 + half;
    if (node >= nNodes) return;
    int cnt = counts[node], off = offsets[node];
    float acc = 0.f;
    for (int base = 0; base < cnt; base += 4) {
        int e = base + eg;
        if (e < cnt) {
            int s = sorted_src[off + e];
            acc += pv[(size_t)s * 8 + c];
        }
    }
    acc += __shfl_xor(acc, 8);
    acc += __shfl_xor(acc, 16);
    if (eg == 0) {
        float inv = 1.0f / fmaxf((float)cnt, 1.0f);
        out[(size_t)node * 8 + c] = acc * inv + qv[(size_t)node * 8 + c] + bl2[c];
    }
}

static inline size_t align256(size_t v) { return (v + 255) & ~(size_t)255; }

extern "C" void kernel_launch(void* const* d_in, const int* in_sizes, int n_in,
                              void* d_out, int out_size, void* d_ws, size_t ws_size,
                              hipStream_t stream) {
    const float* embeds = (const float*)d_in[0];
    const int*   ei     = (const int*)d_in[1];
    const float* Wl1    = (const float*)d_in[2];
    const float* bl1    = (const float*)d_in[3];
    const float* Wr1    = (const float*)d_in[4];
    const float* Wl2    = (const float*)d_in[5];
    const float* bl2    = (const float*)d_in[6];
    const float* Wr2    = (const float*)d_in[7];

    const int N = in_sizes[0] / N_FEATS;     // 50000
    const int E = in_sizes[1] / 2;           // 800000
    const int* src = ei;
    const int* dst = ei + E;
    const int E4 = E / 4;
    const int NB = (N + 255) / 256;          // scan blocks

    // workspace layout
    char* ws = (char*)d_ws;
    size_t off = 0;
    int*   counts     = (int*)(ws + off); off += align256((size_t)N * sizeof(int));
    int*   offsets    = (int*)(ws + off); off += align256((size_t)N * sizeof(int));
    int*   cursor     = (int*)(ws + off); off += align256((size_t)N * sizeof(int));
    int*   partials   = (int*)(ws + off); off += align256((size_t)256 * sizeof(int));
    int*   sorted_src = (int*)(ws + off); off += align256((size_t)E * sizeof(int));
    float* u          = (float*)(ws + off); off += align256((size_t)N * 64 * sizeof(float));
    float* v          = (float*)(ws + off); off += align256((size_t)N * 64 * sizeof(float));
    float* p          = (float*)(ws + off); off += align256((size_t)N * 8 * sizeof(float));
    float* q          = (float*)(ws + off); off += align256((size_t)N * 8 * sizeof(float));
    (void)ws_size;

    hipMemsetAsync(counts, 0, (size_t)N * sizeof(int), stream);

    {   // dense projections u = X@Wl1, v = X@Wr1 + b (independent of CSR)
        int blocks = (N + 127) / 128;
        k_gemm<<<blocks, 128, 0, stream>>>(embeds, Wl1, bl1, Wr1, u, v, N);
    }
    {   // degree histogram (int4)
        int threads = E4 + 1;
        int blocks = (threads + 255) / 256;
        k_hist<<<blocks, 256, 0, stream>>>(dst, counts, E4, E);
    }
    // two-level exclusive scan -> offsets, cursor
    k_partial<<<NB, 256, 0, stream>>>(counts, partials, N);
    k_root<<<1, 256, 0, stream>>>(partials, NB);
    k_offsets<<<NB, 256, 0, stream>>>(counts, partials, offsets, cursor, N);
    {   // bucket sort edges by dst (int4)
        int threads = E4 + 1;
        int blocks = (threads + 255) / 256;
        k_bucket<<<blocks, 256, 0, stream>>>(src, dst, cursor, sorted_src, E4, E);
    }
    {   // gather-mean(u) + v -> p,q   (1 node/wave, 4 nodes/block)
        int blocks = (N + 3) / 4;
        k_gather1<<<blocks, 256, 0, stream>>>(u, v, counts, offsets, sorted_src,
                                              Wl2, Wr2, p, q, N);
    }
    {   // layer-2 gather-aggregate + epilogue (8 nodes/block)
        int blocks = (N + 7) / 8;
        k_final<<<blocks, 256, 0, stream>>>(p, q, counts, offsets, sorted_src,
                                            bl2, (float*)d_out, N);
    }
}

// Round 7
// 127.081 us; speedup vs baseline: 2.7125x; 1.4480x over previous
//
#include <hip/hip_runtime.h>
#include <hip/hip_bf16.h>
#include <cstddef>

#define N_FEATS 64
#define NBKT_SHIFT 8      // coarse bucket = dst >> 8  (256 nodes per bucket)
#define EPB1 4096         // edges per phase-1 block

// ---------------------------------------------------------------------------
// Phase 1a: per-block coarse histogram -> H[bucket][block]  (bucket-major)
// ---------------------------------------------------------------------------
__global__ __launch_bounds__(256) void k_chist(const int* __restrict__ dst,
                                               int* __restrict__ H,
                                               int nEdges, int nbkt, int nb1) {
    __shared__ int lh[256];
    int tid = threadIdx.x, blk = blockIdx.x;
    lh[tid] = 0;
    __syncthreads();
    int base = blk * EPB1;
    #pragma unroll
    for (int j = 0; j < EPB1 / 256; ++j) {
        int e = base + j * 256 + tid;
        if (e < nEdges) atomicAdd(&lh[((unsigned)dst[e]) >> NBKT_SHIFT], 1);
    }
    __syncthreads();
    if (tid < nbkt) H[tid * nb1 + blk] = lh[tid];
}

// ---------------------------------------------------------------------------
// Two-level exclusive scan (reused pattern): partial reduce, root scan,
// per-block exclusive scan + base -> single output array.
// ---------------------------------------------------------------------------
__global__ __launch_bounds__(256) void k_partial(const int* __restrict__ in,
                                                 int* __restrict__ partials, int n) {
    __shared__ int sdata[256];
    int tid = threadIdx.x;
    int i = blockIdx.x * 256 + tid;
    sdata[tid] = (i < n) ? in[i] : 0;
    __syncthreads();
    for (int s = 128; s > 0; s >>= 1) {
        if (tid < s) sdata[tid] += sdata[tid + s];
        __syncthreads();
    }
    if (tid == 0) partials[blockIdx.x] = sdata[0];
}

__global__ __launch_bounds__(256) void k_root(int* __restrict__ partials, int nb) {
    __shared__ int sdata[256];
    int tid = threadIdx.x;
    sdata[tid] = (tid < nb) ? partials[tid] : 0;
    __syncthreads();
    for (int d = 1; d < 256; d <<= 1) {
        int t = (tid >= d) ? sdata[tid - d] : 0;
        __syncthreads();
        sdata[tid] += t;
        __syncthreads();
    }
    if (tid < nb) partials[tid] = (tid == 0) ? 0 : sdata[tid - 1];
}

__global__ __launch_bounds__(256) void k_offsets2(const int* __restrict__ in,
                                                  const int* __restrict__ partials,
                                                  int* __restrict__ out, int n) {
    __shared__ int sdata[256];
    int tid = threadIdx.x;
    int i = blockIdx.x * 256 + tid;
    int v = (i < n) ? in[i] : 0;
    sdata[tid] = v;
    __syncthreads();
    for (int d = 1; d < 256; d <<= 1) {
        int t = (tid >= d) ? sdata[tid - d] : 0;
        __syncthreads();
        sdata[tid] += t;
        __syncthreads();
    }
    int excl = sdata[tid] - v + partials[blockIdx.x];
    if (i < n) out[i] = excl;
}

// ---------------------------------------------------------------------------
// Phase 1b: multisplit -> pairs[] grouped by coarse bucket; per-(bucket,block)
// cells are contiguous, cursors live in LDS (no global atomics).
// ---------------------------------------------------------------------------
__global__ __launch_bounds__(256) void k_split(const int* __restrict__ src,
                                               const int* __restrict__ dst,
                                               const int* __restrict__ HO,
                                               int2* __restrict__ pairs,
                                               int nEdges, int nbkt, int nb1) {
    __shared__ int cur[256];
    int tid = threadIdx.x, blk = blockIdx.x;
    if (tid < nbkt) cur[tid] = HO[tid * nb1 + blk];
    __syncthreads();
    int base = blk * EPB1;
    #pragma unroll
    for (int j = 0; j < EPB1 / 256; ++j) {
        int e = base + j * 256 + tid;
        if (e < nEdges) {
            int d = dst[e];
            int pos = atomicAdd(&cur[((unsigned)d) >> NBKT_SHIFT], 1);
            pairs[pos] = make_int2(src[e], d);
        }
    }
}

// ---------------------------------------------------------------------------
// Phase 2: one block per coarse bucket; counting sort by dst&255 in LDS.
// Emits counts[], offsets[], sorted_src[] — all writes block-region-local.
// ---------------------------------------------------------------------------
__global__ __launch_bounds__(256) void k_fsort(const int2* __restrict__ pairs,
                                               const int* __restrict__ HO,
                                               int* __restrict__ counts,
                                               int* __restrict__ offsets,
                                               int* __restrict__ sorted_src,
                                               int nEdges, int nNodes,
                                               int nbkt, int nb1) {
    __shared__ int cnt[256];
    __shared__ int scanbuf[256];
    __shared__ int cur[256];
    int tid = threadIdx.x, b = blockIdx.x;
    int bStart = HO[b * nb1];
    int bEnd = (b + 1 < nbkt) ? HO[(b + 1) * nb1] : nEdges;
    cnt[tid] = 0;
    __syncthreads();
    for (int e = bStart + tid; e < bEnd; e += 256) {
        atomicAdd(&cnt[pairs[e].y & 255], 1);
    }
    __syncthreads();
    int v = cnt[tid];
    scanbuf[tid] = v;
    __syncthreads();
    for (int d = 1; d < 256; d <<= 1) {
        int t = (tid >= d) ? scanbuf[tid - d] : 0;
        __syncthreads();
        scanbuf[tid] += t;
        __syncthreads();
    }
    int excl = scanbuf[tid] - v;
    int node = (b << NBKT_SHIFT) + tid;
    if (node < nNodes) { counts[node] = v; offsets[node] = bStart + excl; }
    cur[tid] = bStart + excl;
    __syncthreads();
    for (int e = bStart + tid; e < bEnd; e += 256) {
        int2 pr = pairs[e];
        int pos = atomicAdd(&cur[pr.y & 255], 1);
        sorted_src[pos] = pr.x;
    }
}

// ---------------------------------------------------------------------------
// Dense projections  u = X@Wl1,  v = X@Wr1 + b.  (unchanged)
// ---------------------------------------------------------------------------
__global__ __launch_bounds__(128) void k_gemm(
        const float* __restrict__ x,
        const float* __restrict__ Wl1,
        const float* __restrict__ bl1,
        const float* __restrict__ Wr1,
        float* __restrict__ u,
        float* __restrict__ v,
        int nNodes) {
    __shared__ float sWl[64 * 64];
    __shared__ float sWr[64 * 64];
    __shared__ float sb[64];

    int tid = threadIdx.x;
    for (int i = tid; i < 1024; i += 128) {
        ((float4*)sWl)[i] = ((const float4*)Wl1)[i];
        ((float4*)sWr)[i] = ((const float4*)Wr1)[i];
    }
    if (tid < 64) sb[tid] = bl1[tid];
    __syncthreads();

    int wave = tid >> 6, lane = tid & 63;
    int node = blockIdx.x * 128 + wave * 64 + lane;
    bool valid = (node < nNodes);

    float4 vx[16];
    const float4* xv4 = (const float4*)x;
    if (valid) {
        #pragma unroll
        for (int j = 0; j < 16; ++j) vx[j] = xv4[(size_t)node * 16 + j];
    } else {
        #pragma unroll
        for (int j = 0; j < 16; ++j) vx[j] = make_float4(0.f, 0.f, 0.f, 0.f);
    }

    #pragma unroll 1
    for (int fc = 0; fc < 8; ++fc) {
        int f0 = fc * 8;
        float au0=0.f,au1=0.f,au2=0.f,au3=0.f,au4=0.f,au5=0.f,au6=0.f,au7=0.f;
        float av0,av1,av2,av3,av4,av5,av6,av7;
        {
            float4 b0 = *(const float4*)&sb[f0];
            float4 b1 = *(const float4*)&sb[f0 + 4];
            av0=b0.x; av1=b0.y; av2=b0.z; av3=b0.w;
            av4=b1.x; av5=b1.y; av6=b1.z; av7=b1.w;
        }
        #pragma unroll
        for (int k4 = 0; k4 < 16; ++k4) {
            float4 xq = vx[k4];
            #pragma unroll
            for (int kk = 0; kk < 4; ++kk) {
                int k = k4 * 4 + kk;
                float xk = (kk == 0) ? xq.x : (kk == 1) ? xq.y : (kk == 2) ? xq.z : xq.w;
                float4 wl0 = *(const float4*)&sWl[k * 64 + f0];
                float4 wl1v = *(const float4*)&sWl[k * 64 + f0 + 4];
                float4 wr0 = *(const float4*)&sWr[k * 64 + f0];
                float4 wr1v = *(const float4*)&sWr[k * 64 + f0 + 4];
                au0 += xk * wl0.x;  au1 += xk * wl0.y;
                au2 += xk * wl0.z;  au3 += xk * wl0.w;
                au4 += xk * wl1v.x; au5 += xk * wl1v.y;
                au6 += xk * wl1v.z; au7 += xk * wl1v.w;
                av0 += xk * wr0.x;  av1 += xk * wr0.y;
                av2 += xk * wr0.z;  av3 += xk * wr0.w;
                av4 += xk * wr1v.x; av5 += xk * wr1v.y;
                av6 += xk * wr1v.z; av7 += xk * wr1v.w;
            }
        }
        if (valid) {
            float4 s;
            s.x=au0; s.y=au1; s.z=au2; s.w=au3;
            ((float4*)u)[(size_t)node * 16 + fc * 2]     = s;
            s.x=au4; s.y=au5; s.z=au6; s.w=au7;
            ((float4*)u)[(size_t)node * 16 + fc * 2 + 1] = s;
            s.x=av0; s.y=av1; s.z=av2; s.w=av3;
            ((float4*)v)[(size_t)node * 16 + fc * 2]     = s;
            s.x=av4; s.y=av5; s.z=av6; s.w=av7;
            ((float4*)v)[(size_t)node * 16 + fc * 2 + 1] = s;
        }
    }
}

// ---------------------------------------------------------------------------
// h = mean-gather(u) + v;  p = h@Wl2; q = h@Wr2.  (unchanged)
// ---------------------------------------------------------------------------
__global__ __launch_bounds__(256) void k_gather1(
        const float* __restrict__ u,
        const float* __restrict__ v,
        const int* __restrict__ counts,
        const int* __restrict__ offsets,
        const int* __restrict__ sorted_src,
        const float* __restrict__ Wl2,
        const float* __restrict__ Wr2,
        float* __restrict__ p,
        float* __restrict__ q,
        int nNodes) {
    __shared__ float sWl2[64 * 9];
    __shared__ float sWr2[64 * 9];
    __shared__ float sh[4][64];

    int tid = threadIdx.x;
    for (int i = tid; i < 64 * 8; i += 256) {
        int k = i >> 3, c = i & 7;
        sWl2[k * 9 + c] = Wl2[i];
        sWr2[k * 9 + c] = Wr2[i];
    }
    __syncthreads();

    int slot = tid >> 6;
    int f    = tid & 63;
    int g    = f >> 4;
    int t4   = f & 15;
    const float4* uv4 = (const float4*)u;

    int node = blockIdx.x * 4 + slot;
    if (node >= nNodes) return;
    int cnt = counts[node];
    int off = offsets[node];

    float ax = 0.f, ay = 0.f, az = 0.f, aw = 0.f;
    int id = (g < cnt) ? sorted_src[off + g] : -1;
    for (int base = 0; base < cnt; base += 4) {
        int en  = base + 4 + g;
        int idn = (en < cnt) ? sorted_src[off + en] : -1;
        if (id >= 0) {
            float4 r = uv4[(size_t)id * 16 + t4];
            ax += r.x; ay += r.y; az += r.z; aw += r.w;
        }
        id = idn;
    }
    ax += __shfl_xor(ax, 16); ay += __shfl_xor(ay, 16);
    az += __shfl_xor(az, 16); aw += __shfl_xor(aw, 16);
    ax += __shfl_xor(ax, 32); ay += __shfl_xor(ay, 32);
    az += __shfl_xor(az, 32); aw += __shfl_xor(aw, 32);

    if (g == 0) {
        float inv = 1.0f / fmaxf((float)cnt, 1.0f);
        float4 vr = ((const float4*)v)[(size_t)node * 16 + t4];
        float4 o;
        o.x = ax * inv + vr.x; o.y = ay * inv + vr.y;
        o.z = az * inv + vr.z; o.w = aw * inv + vr.w;
        ((float4*)sh[slot])[t4] = o;
    }

    int pq = f >> 5, c = (f >> 2) & 7, kp = f & 3;
    const float* W = pq ? sWr2 : sWl2;
    float a2 = 0.f;
    #pragma unroll
    for (int kk = 0; kk < 16; ++kk) {
        int k = kp * 16 + kk;
        a2 += sh[slot][k] * W[k * 9 + c];
    }
    a2 += __shfl_xor(a2, 1);
    a2 += __shfl_xor(a2, 2);
    if (kp == 0) {
        if (pq == 0) p[(size_t)node * 8 + c] = a2;
        else         q[(size_t)node * 8 + c] = a2;
    }
}

// ---------------------------------------------------------------------------
// Layer-2 gather-mean of p + epilogue. (unchanged)
// ---------------------------------------------------------------------------
__global__ __launch_bounds__(256) void k_final(
        const float* __restrict__ pv,
        const float* __restrict__ qv,
        const int* __restrict__ counts,
        const int* __restrict__ offsets,
        const int* __restrict__ sorted_src,
        const float* __restrict__ bl2,
        float* __restrict__ out,
        int nNodes) {
    int tid  = threadIdx.x;
    int wave = tid >> 6, lane = tid & 63;
    int half = lane >> 5;
    int eg   = (lane >> 3) & 3;
    int c    = lane & 7;
    int node = blockIdx.x * 8 + wave * 2 + half;
    if (node >= nNodes) return;
    int cnt = counts[node], off = offsets[node];
    float acc = 0.f;
    for (int base = 0; base < cnt; base += 4) {
        int e = base + eg;
        if (e < cnt) {
            int s = sorted_src[off + e];
            acc += pv[(size_t)s * 8 + c];
        }
    }
    acc += __shfl_xor(acc, 8);
    acc += __shfl_xor(acc, 16);
    if (eg == 0) {
        float inv = 1.0f / fmaxf((float)cnt, 1.0f);
        out[(size_t)node * 8 + c] = acc * inv + qv[(size_t)node * 8 + c] + bl2[c];
    }
}

static inline size_t align256(size_t v) { return (v + 255) & ~(size_t)255; }

extern "C" void kernel_launch(void* const* d_in, const int* in_sizes, int n_in,
                              void* d_out, int out_size, void* d_ws, size_t ws_size,
                              hipStream_t stream) {
    const float* embeds = (const float*)d_in[0];
    const int*   ei     = (const int*)d_in[1];
    const float* Wl1    = (const float*)d_in[2];
    const float* bl1    = (const float*)d_in[3];
    const float* Wr1    = (const float*)d_in[4];
    const float* Wl2    = (const float*)d_in[5];
    const float* bl2    = (const float*)d_in[6];
    const float* Wr2    = (const float*)d_in[7];

    const int N = in_sizes[0] / N_FEATS;           // 50000
    const int E = in_sizes[1] / 2;                 // 800000
    const int* src = ei;
    const int* dst = ei + E;

    const int NBKT = (N + 255) >> NBKT_SHIFT;      // 196 coarse buckets
    const int NB1  = (E + EPB1 - 1) / EPB1;        // 196 phase-1 blocks
    const int M    = NBKT * NB1;                   // 38416 hist-matrix entries
    const int NBs  = (M + 255) / 256;              // 151 scan blocks

    // workspace layout (pairs aliases u: pairs dead before k_gemm writes u)
    char* ws = (char*)d_ws;
    size_t off = 0;
    int*   counts     = (int*)(ws + off); off += align256((size_t)N * sizeof(int));
    int*   offsets    = (int*)(ws + off); off += align256((size_t)N * sizeof(int));
    int*   partials   = (int*)(ws + off); off += align256((size_t)256 * sizeof(int));
    int*   H          = (int*)(ws + off); off += align256((size_t)M * sizeof(int));
    int*   HO         = (int*)(ws + off); off += align256((size_t)M * sizeof(int));
    int*   sorted_src = (int*)(ws + off); off += align256((size_t)E * sizeof(int));
    float* u          = (float*)(ws + off);
    int2*  pairs      = (int2*)(ws + off); off += align256((size_t)N * 64 * sizeof(float));
    float* v          = (float*)(ws + off); off += align256((size_t)N * 64 * sizeof(float));
    float* p          = (float*)(ws + off); off += align256((size_t)N * 8 * sizeof(float));
    float* q          = (float*)(ws + off); off += align256((size_t)N * 8 * sizeof(float));
    (void)ws_size;

    // CSR build: coarse hist -> scan -> multisplit -> per-bucket counting sort
    k_chist<<<NB1, 256, 0, stream>>>(dst, H, E, NBKT, NB1);
    k_partial<<<NBs, 256, 0, stream>>>(H, partials, M);
    k_root<<<1, 256, 0, stream>>>(partials, NBs);
    k_offsets2<<<NBs, 256, 0, stream>>>(H, partials, HO, M);
    k_split<<<NB1, 256, 0, stream>>>(src, dst, HO, pairs, E, NBKT, NB1);
    k_fsort<<<NBKT, 256, 0, stream>>>(pairs, HO, counts, offsets, sorted_src,
                                      E, N, NBKT, NB1);
    // dense projections (after k_fsort: u aliases pairs)
    {
        int blocks = (N + 127) / 128;
        k_gemm<<<blocks, 128, 0, stream>>>(embeds, Wl1, bl1, Wr1, u, v, N);
    }
    {   // gather-mean(u) + v -> p,q
        int blocks = (N + 3) / 4;
        k_gather1<<<blocks, 256, 0, stream>>>(u, v, counts, offsets, sorted_src,
                                              Wl2, Wr2, p, q, N);
    }
    {   // layer-2 gather + epilogue
        int blocks = (N + 7) / 8;
        k_final<<<blocks, 256, 0, stream>>>(p, q, counts, offsets, sorted_src,
                                            bl2, (float*)d_out, N);
    }
}

// Round 8
// 124.833 us; speedup vs baseline: 2.7614x; 1.0180x over previous
//
#include <hip/hip_runtime.h>
#include <hip/hip_bf16.h>
#include <cstddef>

#define N_FEATS 64
#define NBKT_SHIFT 8      // coarse bucket = dst >> 8  (256 nodes per bucket)
#define EPB1 4096         // edges per phase-1 block

// round-to-nearest-even f32 -> bf16 bits (values are finite/sane here)
__device__ __forceinline__ unsigned f2bf(float f) {
    unsigned x = __float_as_uint(f);
    return (x + 0x7fffu + ((x >> 16) & 1u)) >> 16;
}

// ---------------------------------------------------------------------------
// Phase 1a: per-block coarse histogram -> H[bucket][block]  (bucket-major)
// ---------------------------------------------------------------------------
__global__ __launch_bounds__(256) void k_chist(const int* __restrict__ dst,
                                               int* __restrict__ H,
                                               int nEdges, int nbkt, int nb1) {
    __shared__ int lh[256];
    int tid = threadIdx.x, blk = blockIdx.x;
    lh[tid] = 0;
    __syncthreads();
    int base = blk * EPB1;
    #pragma unroll
    for (int j = 0; j < EPB1 / 256; ++j) {
        int e = base + j * 256 + tid;
        if (e < nEdges) atomicAdd(&lh[((unsigned)dst[e]) >> NBKT_SHIFT], 1);
    }
    __syncthreads();
    if (tid < nbkt) H[tid * nb1 + blk] = lh[tid];
}

// ---------------------------------------------------------------------------
// Scan: per-block partial sums, then per-block exclusive scan where each
// block derives its own base from the partials (no separate root kernel).
// ---------------------------------------------------------------------------
__global__ __launch_bounds__(256) void k_partial(const int* __restrict__ in,
                                                 int* __restrict__ partials, int n) {
    __shared__ int sdata[256];
    int tid = threadIdx.x;
    int i = blockIdx.x * 256 + tid;
    sdata[tid] = (i < n) ? in[i] : 0;
    __syncthreads();
    for (int s = 128; s > 0; s >>= 1) {
        if (tid < s) sdata[tid] += sdata[tid + s];
        __syncthreads();
    }
    if (tid == 0) partials[blockIdx.x] = sdata[0];
}

__global__ __launch_bounds__(256) void k_offsets2(const int* __restrict__ in,
                                                  const int* __restrict__ partials,
                                                  int* __restrict__ out, int n) {
    __shared__ int sdata[256];
    __shared__ int sbase[256];
    int tid = threadIdx.x;
    int i = blockIdx.x * 256 + tid;
    // base = sum of partials[0 .. blockIdx.x)
    int b = 0;
    for (int j = tid; j < blockIdx.x; j += 256) b += partials[j];
    sbase[tid] = b;
    int v = (i < n) ? in[i] : 0;
    sdata[tid] = v;
    __syncthreads();
    for (int s = 128; s > 0; s >>= 1) {
        if (tid < s) sbase[tid] += sbase[tid + s];
        __syncthreads();
    }
    for (int d = 1; d < 256; d <<= 1) {
        int t = (tid >= d) ? sdata[tid - d] : 0;
        __syncthreads();
        sdata[tid] += t;
        __syncthreads();
    }
    int excl = sdata[tid] - v + sbase[0];
    if (i < n) out[i] = excl;
}

// ---------------------------------------------------------------------------
// Phase 1b: multisplit -> pairs[] grouped by coarse bucket; per-(bucket,block)
// cells are contiguous, cursors live in LDS (no global atomics).
// ---------------------------------------------------------------------------
__global__ __launch_bounds__(256) void k_split(const int* __restrict__ src,
                                               const int* __restrict__ dst,
                                               const int* __restrict__ HO,
                                               int2* __restrict__ pairs,
                                               int nEdges, int nbkt, int nb1) {
    __shared__ int cur[256];
    int tid = threadIdx.x, blk = blockIdx.x;
    if (tid < nbkt) cur[tid] = HO[tid * nb1 + blk];
    __syncthreads();
    int base = blk * EPB1;
    #pragma unroll
    for (int j = 0; j < EPB1 / 256; ++j) {
        int e = base + j * 256 + tid;
        if (e < nEdges) {
            int d = dst[e];
            int pos = atomicAdd(&cur[((unsigned)d) >> NBKT_SHIFT], 1);
            pairs[pos] = make_int2(src[e], d);
        }
    }
}

// ---------------------------------------------------------------------------
// Phase 2: one block per coarse bucket; counting sort by dst&255 in LDS.
// Emits counts[], offsets[], sorted_src[] — all writes block-region-local.
// ---------------------------------------------------------------------------
__global__ __launch_bounds__(256) void k_fsort(const int2* __restrict__ pairs,
                                               const int* __restrict__ HO,
                                               int* __restrict__ counts,
                                               int* __restrict__ offsets,
                                               int* __restrict__ sorted_src,
                                               int nEdges, int nNodes,
                                               int nbkt, int nb1) {
    __shared__ int cnt[256];
    __shared__ int scanbuf[256];
    __shared__ int cur[256];
    int tid = threadIdx.x, b = blockIdx.x;
    int bStart = HO[b * nb1];
    int bEnd = (b + 1 < nbkt) ? HO[(b + 1) * nb1] : nEdges;
    cnt[tid] = 0;
    __syncthreads();
    for (int e = bStart + tid; e < bEnd; e += 256) {
        atomicAdd(&cnt[pairs[e].y & 255], 1);
    }
    __syncthreads();
    int v = cnt[tid];
    scanbuf[tid] = v;
    __syncthreads();
    for (int d = 1; d < 256; d <<= 1) {
        int t = (tid >= d) ? scanbuf[tid - d] : 0;
        __syncthreads();
        scanbuf[tid] += t;
        __syncthreads();
    }
    int excl = scanbuf[tid] - v;
    int node = (b << NBKT_SHIFT) + tid;
    if (node < nNodes) { counts[node] = v; offsets[node] = bStart + excl; }
    cur[tid] = bStart + excl;
    __syncthreads();
    for (int e = bStart + tid; e < bEnd; e += 256) {
        int2 pr = pairs[e];
        int pos = atomicAdd(&cur[pr.y & 255], 1);
        sorted_src[pos] = pr.x;
    }
}

// ---------------------------------------------------------------------------
// Dense projections  u = X@Wl1 (bf16 out),  v = X@Wr1 + b (f32 out).
// ---------------------------------------------------------------------------
__global__ __launch_bounds__(128) void k_gemm(
        const float* __restrict__ x,
        const float* __restrict__ Wl1,
        const float* __restrict__ bl1,
        const float* __restrict__ Wr1,
        unsigned* __restrict__ u,      // bf16 pairs: N x 32 uints (64 bf16/row)
        float* __restrict__ v,
        int nNodes) {
    __shared__ float sWl[64 * 64];
    __shared__ float sWr[64 * 64];
    __shared__ float sb[64];

    int tid = threadIdx.x;
    for (int i = tid; i < 1024; i += 128) {
        ((float4*)sWl)[i] = ((const float4*)Wl1)[i];
        ((float4*)sWr)[i] = ((const float4*)Wr1)[i];
    }
    if (tid < 64) sb[tid] = bl1[tid];
    __syncthreads();

    int wave = tid >> 6, lane = tid & 63;
    int node = blockIdx.x * 128 + wave * 64 + lane;
    bool valid = (node < nNodes);

    float4 vx[16];
    const float4* xv4 = (const float4*)x;
    if (valid) {
        #pragma unroll
        for (int j = 0; j < 16; ++j) vx[j] = xv4[(size_t)node * 16 + j];
    } else {
        #pragma unroll
        for (int j = 0; j < 16; ++j) vx[j] = make_float4(0.f, 0.f, 0.f, 0.f);
    }

    #pragma unroll 1
    for (int fc = 0; fc < 8; ++fc) {
        int f0 = fc * 8;
        float au0=0.f,au1=0.f,au2=0.f,au3=0.f,au4=0.f,au5=0.f,au6=0.f,au7=0.f;
        float av0,av1,av2,av3,av4,av5,av6,av7;
        {
            float4 b0 = *(const float4*)&sb[f0];
            float4 b1 = *(const float4*)&sb[f0 + 4];
            av0=b0.x; av1=b0.y; av2=b0.z; av3=b0.w;
            av4=b1.x; av5=b1.y; av6=b1.z; av7=b1.w;
        }
        #pragma unroll
        for (int k4 = 0; k4 < 16; ++k4) {
            float4 xq = vx[k4];
            #pragma unroll
            for (int kk = 0; kk < 4; ++kk) {
                int k = k4 * 4 + kk;
                float xk = (kk == 0) ? xq.x : (kk == 1) ? xq.y : (kk == 2) ? xq.z : xq.w;
                float4 wl0 = *(const float4*)&sWl[k * 64 + f0];
                float4 wl1v = *(const float4*)&sWl[k * 64 + f0 + 4];
                float4 wr0 = *(const float4*)&sWr[k * 64 + f0];
                float4 wr1v = *(const float4*)&sWr[k * 64 + f0 + 4];
                au0 += xk * wl0.x;  au1 += xk * wl0.y;
                au2 += xk * wl0.z;  au3 += xk * wl0.w;
                au4 += xk * wl1v.x; au5 += xk * wl1v.y;
                au6 += xk * wl1v.z; au7 += xk * wl1v.w;
                av0 += xk * wr0.x;  av1 += xk * wr0.y;
                av2 += xk * wr0.z;  av3 += xk * wr0.w;
                av4 += xk * wr1v.x; av5 += xk * wr1v.y;
                av6 += xk * wr1v.z; av7 += xk * wr1v.w;
            }
        }
        if (valid) {
            uint4 s;
            s.x = f2bf(au0) | (f2bf(au1) << 16);
            s.y = f2bf(au2) | (f2bf(au3) << 16);
            s.z = f2bf(au4) | (f2bf(au5) << 16);
            s.w = f2bf(au6) | (f2bf(au7) << 16);
            ((uint4*)u)[(size_t)node * 8 + fc] = s;   // 8 bf16 = 16B per chunk
            float4 t;
            t.x=av0; t.y=av1; t.z=av2; t.w=av3;
            ((float4*)v)[(size_t)node * 16 + fc * 2]     = t;
            t.x=av4; t.y=av5; t.z=av6; t.w=av7;
            ((float4*)v)[(size_t)node * 16 + fc * 2 + 1] = t;
        }
    }
}

// ---------------------------------------------------------------------------
// h = mean-gather(u: bf16) + v;  p = h@Wl2; q = h@Wr2.
// 1 node/wave; 16 lanes x 8B per u-row (128B), 4 edge-groups in parallel.
// ---------------------------------------------------------------------------
__global__ __launch_bounds__(256) void k_gather1(
        const unsigned* __restrict__ u,
        const float* __restrict__ v,
        const int* __restrict__ counts,
        const int* __restrict__ offsets,
        const int* __restrict__ sorted_src,
        const float* __restrict__ Wl2,
        const float* __restrict__ Wr2,
        float* __restrict__ p,
        float* __restrict__ q,
        int nNodes) {
    __shared__ float sWl2[64 * 9];
    __shared__ float sWr2[64 * 9];
    __shared__ float sh[4][64];

    int tid = threadIdx.x;
    for (int i = tid; i < 64 * 8; i += 256) {
        int k = i >> 3, c = i & 7;
        sWl2[k * 9 + c] = Wl2[i];
        sWr2[k * 9 + c] = Wr2[i];
    }
    __syncthreads();

    int slot = tid >> 6;
    int f    = tid & 63;
    int g    = f >> 4;     // edge group
    int t4   = f & 15;     // 4-element slot within the 64-elem row
    const uint2* uv2 = (const uint2*)u;   // 16 x uint2 (8B) per row

    int node = blockIdx.x * 4 + slot;
    if (node >= nNodes) return;
    int cnt = counts[node];
    int off = offsets[node];

    float ax = 0.f, ay = 0.f, az = 0.f, aw = 0.f;
    int id = (g < cnt) ? sorted_src[off + g] : -1;
    for (int base = 0; base < cnt; base += 4) {
        int en  = base + 4 + g;
        int idn = (en < cnt) ? sorted_src[off + en] : -1;
        if (id >= 0) {
            uint2 r = uv2[(size_t)id * 16 + t4];
            ax += __uint_as_float(r.x << 16);
            ay += __uint_as_float(r.x & 0xffff0000u);
            az += __uint_as_float(r.y << 16);
            aw += __uint_as_float(r.y & 0xffff0000u);
        }
        id = idn;
    }
    ax += __shfl_xor(ax, 16); ay += __shfl_xor(ay, 16);
    az += __shfl_xor(az, 16); aw += __shfl_xor(aw, 16);
    ax += __shfl_xor(ax, 32); ay += __shfl_xor(ay, 32);
    az += __shfl_xor(az, 32); aw += __shfl_xor(aw, 32);

    if (g == 0) {
        float inv = 1.0f / fmaxf((float)cnt, 1.0f);
        float4 vr = ((const float4*)v)[(size_t)node * 16 + t4];
        float4 o;
        o.x = ax * inv + vr.x; o.y = ay * inv + vr.y;
        o.z = az * inv + vr.z; o.w = aw * inv + vr.w;
        ((float4*)sh[slot])[t4] = o;
    }
    // intra-wave LDS dependency: compiler orders via lgkmcnt; no barrier.

    int pq = f >> 5, c = (f >> 2) & 7, kp = f & 3;
    const float* W = pq ? sWr2 : sWl2;
    float a2 = 0.f;
    #pragma unroll
    for (int kk = 0; kk < 16; ++kk) {
        int k = kp * 16 + kk;
        a2 += sh[slot][k] * W[k * 9 + c];
    }
    a2 += __shfl_xor(a2, 1);
    a2 += __shfl_xor(a2, 2);
    if (kp == 0) {
        if (pq == 0) p[(size_t)node * 8 + c] = a2;
        else         q[(size_t)node * 8 + c] = a2;
    }
}

// ---------------------------------------------------------------------------
// Layer-2 gather-mean of p + epilogue. 2 nodes per wave.
// ---------------------------------------------------------------------------
__global__ __launch_bounds__(256) void k_final(
        const float* __restrict__ pv,
        const float* __restrict__ qv,
        const int* __restrict__ counts,
        const int* __restrict__ offsets,
        const int* __restrict__ sorted_src,
        const float* __restrict__ bl2,
        float* __restrict__ out,
        int nNodes) {
    int tid  = threadIdx.x;
    int wave = tid >> 6, lane = tid & 63;
    int half = lane >> 5;
    int eg   = (lane >> 3) & 3;
    int c    = lane & 7;
    int node = blockIdx.x * 8 + wave * 2 + half;
    if (node >= nNodes) return;
    int cnt = counts[node], off = offsets[node];
    float acc = 0.f;
    for (int base = 0; base < cnt; base += 4) {
        int e = base + eg;
        if (e < cnt) {
            int s = sorted_src[off + e];
            acc += pv[(size_t)s * 8 + c];
        }
    }
    acc += __shfl_xor(acc, 8);
    acc += __shfl_xor(acc, 16);
    if (eg == 0) {
        float inv = 1.0f / fmaxf((float)cnt, 1.0f);
        out[(size_t)node * 8 + c] = acc * inv + qv[(size_t)node * 8 + c] + bl2[c];
    }
}

static inline size_t align256(size_t v) { return (v + 255) & ~(size_t)255; }

extern "C" void kernel_launch(void* const* d_in, const int* in_sizes, int n_in,
                              void* d_out, int out_size, void* d_ws, size_t ws_size,
                              hipStream_t stream) {
    const float* embeds = (const float*)d_in[0];
    const int*   ei     = (const int*)d_in[1];
    const float* Wl1    = (const float*)d_in[2];
    const float* bl1    = (const float*)d_in[3];
    const float* Wr1    = (const float*)d_in[4];
    const float* Wl2    = (const float*)d_in[5];
    const float* bl2    = (const float*)d_in[6];
    const float* Wr2    = (const float*)d_in[7];

    const int N = in_sizes[0] / N_FEATS;           // 50000
    const int E = in_sizes[1] / 2;                 // 800000
    const int* src = ei;
    const int* dst = ei + E;

    const int NBKT = (N + 255) >> NBKT_SHIFT;      // 196 coarse buckets
    const int NB1  = (E + EPB1 - 1) / EPB1;        // 196 phase-1 blocks
    const int M    = NBKT * NB1;                   // 38416 hist-matrix entries
    const int NBs  = (M + 255) / 256;              // 151 scan blocks

    // workspace layout (pairs aliases u: pairs dead before k_gemm writes u)
    char* ws = (char*)d_ws;
    size_t off = 0;
    int*      counts     = (int*)(ws + off); off += align256((size_t)N * sizeof(int));
    int*      offsets    = (int*)(ws + off); off += align256((size_t)N * sizeof(int));
    int*      partials   = (int*)(ws + off); off += align256((size_t)256 * sizeof(int));
    int*      H          = (int*)(ws + off); off += align256((size_t)M * sizeof(int));
    int*      HO         = (int*)(ws + off); off += align256((size_t)M * sizeof(int));
    int*      sorted_src = (int*)(ws + off); off += align256((size_t)E * sizeof(int));
    unsigned* u          = (unsigned*)(ws + off);               // bf16 u: N*64*2 B
    int2*     pairs      = (int2*)(ws + off);                   // aliases u
    {
        size_t usz = (size_t)N * 64 * 2, psz = (size_t)E * sizeof(int2);
        off += align256(usz > psz ? usz : psz);
    }
    float*    v          = (float*)(ws + off); off += align256((size_t)N * 64 * sizeof(float));
    float*    p          = (float*)(ws + off); off += align256((size_t)N * 8 * sizeof(float));
    float*    q          = (float*)(ws + off); off += align256((size_t)N * 8 * sizeof(float));
    (void)ws_size;

    // CSR build: coarse hist -> scan -> multisplit -> per-bucket counting sort
    k_chist<<<NB1, 256, 0, stream>>>(dst, H, E, NBKT, NB1);
    k_partial<<<NBs, 256, 0, stream>>>(H, partials, M);
    k_offsets2<<<NBs, 256, 0, stream>>>(H, partials, HO, M);
    k_split<<<NB1, 256, 0, stream>>>(src, dst, HO, pairs, E, NBKT, NB1);
    k_fsort<<<NBKT, 256, 0, stream>>>(pairs, HO, counts, offsets, sorted_src,
                                      E, N, NBKT, NB1);
    // dense projections (after k_fsort: u aliases pairs)
    {
        int blocks = (N + 127) / 128;
        k_gemm<<<blocks, 128, 0, stream>>>(embeds, Wl1, bl1, Wr1, u, v, N);
    }
    {   // gather-mean(u) + v -> p,q
        int blocks = (N + 3) / 4;
        k_gather1<<<blocks, 256, 0, stream>>>(u, v, counts, offsets, sorted_src,
                                              Wl2, Wr2, p, q, N);
    }
    {   // layer-2 gather + epilogue
        int blocks = (N + 7) / 8;
        k_final<<<blocks, 256, 0, stream>>>(p, q, counts, offsets, sorted_src,
                                            bl2, (float*)d_out, N);
    }
}